// Round 5
// baseline (96.078 us; speedup 1.0000x reference)
//
#include <hip/hip_runtime.h>

#define N_CODECS 1024
#define EPS 1e-8f
#define REP 32                 // one LDS histogram copy per lane-slot
#define HIST_BLOCKS 256        // 1 block/CU
#define HIST_THREADS 1024      // 16 waves/CU (proven R0 occupancy)
#define RED_BLOCKS 64
#define RED_THREADS 1024
#define ROWS_PER_RED (HIST_BLOCKS / RED_BLOCKS)   // 4

// ---------------------------------------------------------------------------
// Kernel 1: CONFLICT-FREE replicated LDS histogram.
// R2's counters showed ~5 extra bank-conflict cycles per wave ds_add (random
// 64-lane scatter into 32 banks, ~4-5-way) -> ~7-8 us/CU of DS serialization;
// R3 proved occupancy/ILP can't hide it (DS pipe is per-CU, shared).
// Fix by construction: 32 interleaved copies, addr = bin*REP + (lane&31),
// so bank = lane&31 always: each wave-atomic hits every bank exactly 2x
// (lanes l and l+32) and 2-way is free on CDNA4. Same-address collisions
// (lane vs lane+32, same bin) are handled by the atomic itself.
// LDS = 1024*32*4 = 128 KiB -> 1 block/CU, 16 waves/CU.
// Memory schedule byte-identical to the proven R0 loop: 2-deep cached int4
// loads, 262144 threads, 16 int4/thread. (NT loads regressed earlier: L3.)
// Init/merge use rotated addressing (bank = (s+t)&31: 2 lanes/bank, free).
// ---------------------------------------------------------------------------
__global__ void __launch_bounds__(HIST_THREADS) hist_partial_kernel(
        const int* __restrict__ idx,
        unsigned int* __restrict__ gpart,   // [HIST_BLOCKS][N_CODECS]
        unsigned int* __restrict__ cnt,     // [N_CODECS]  (zeroed here)
        unsigned int* __restrict__ done,    // [1]         (zeroed here)
        int n4) {
    __shared__ unsigned int lc[N_CODECS * REP];   // 128 KiB

    const int t = threadIdx.x;

    // zero-init: contiguous uint4 stores, conflict-free by contiguity
    uint4* lc4 = (uint4*)lc;
    #pragma unroll
    for (int k = 0; k < (N_CODECS * REP / 4) / HIST_THREADS; ++k)   // 8 iters
        lc4[k * HIST_THREADS + t] = make_uint4(0u, 0u, 0u, 0u);

    if (blockIdx.x == 0) {
        #pragma unroll
        for (int i = t; i < N_CODECS; i += HIST_THREADS) cnt[i] = 0u;
        if (t == 0) done[0] = 0u;
    }
    __syncthreads();

    const int4* __restrict__ idx4 = (const int4*)idx;
    const int S = gridDim.x * HIST_THREADS;       // 262144
    const int sub = t & 31;
    for (int i = blockIdx.x * HIST_THREADS + t; i < n4; i += 2 * S) {
        int4 a = idx4[i];
        int j = i + S;
        bool has_b = (j < n4);
        int4 b = has_b ? idx4[j] : make_int4(0, 0, 0, 0);

        atomicAdd(&lc[(a.x << 5) | sub], 1u);   // bank = sub: conflict-free
        atomicAdd(&lc[(a.y << 5) | sub], 1u);
        atomicAdd(&lc[(a.z << 5) | sub], 1u);
        atomicAdd(&lc[(a.w << 5) | sub], 1u);
        if (has_b) {
            atomicAdd(&lc[(b.x << 5) | sub], 1u);
            atomicAdd(&lc[(b.y << 5) | sub], 1u);
            atomicAdd(&lc[(b.z << 5) | sub], 1u);
            atomicAdd(&lc[(b.w << 5) | sub], 1u);
        }
    }
    __syncthreads();

    // merge 32 copies of bin t, rotated so bank = (s+t)&31 (2 lanes/bank, free)
    unsigned int sum = 0;
    const int base = t << 5;
    #pragma unroll
    for (int s = 0; s < REP; ++s)
        sum += lc[base | ((s + t) & 31)];
    gpart[(size_t)blockIdx.x * N_CODECS + t] = sum;   // coalesced 4 KB store
}

// ---------------------------------------------------------------------------
// Kernel 2: fused reduce + finalize (R4 structure, partials now 1 MB).
// 64 blocks x 1024 threads: block g column-sums rows [4g,4g+4) (coalesced),
// atomicAdds per-bin sums into cnt[1024] (64 adds/bin, pipelined over 1024
// addresses). Ticket-elected last block re-reads cnt via atomicAdd(p,0)
// (RMW at the coherence point — safe under per-XCD L2 non-coherence),
// computes p*log(p+eps), block-reduces, writes exp(-sum).
// ---------------------------------------------------------------------------
__global__ void __launch_bounds__(RED_THREADS) reduce_finalize_kernel(
        const unsigned int* __restrict__ gpart,   // [HIST_BLOCKS][N_CODECS]
        unsigned int* __restrict__ cnt,           // [N_CODECS]
        unsigned int* __restrict__ done,          // [1]
        float* __restrict__ out,
        float invN) {
    int t = threadIdx.x;

    const unsigned int* __restrict__ base =
        gpart + (size_t)(blockIdx.x * ROWS_PER_RED) * N_CODECS;
    unsigned int s0 = 0;
    #pragma unroll
    for (int r = 0; r < ROWS_PER_RED; ++r)
        s0 += base[(size_t)r * N_CODECS + t];
    atomicAdd(&cnt[t], s0);

    // __syncthreads drains vmcnt -> this block's atomics are globally
    // performed before thread 0 publishes the ticket.
    __syncthreads();

    __shared__ unsigned int ticket;
    if (t == 0) {
        __threadfence();                 // release
        ticket = atomicAdd(done, 1u);
    }
    __syncthreads();
    if (ticket != (unsigned int)(RED_BLOCKS - 1)) return;

    // ---- last block: finalize ----
    __threadfence();                     // acquire
    unsigned int c = atomicAdd(&cnt[t], 0u);      // coherent read
    float p = (float)c * invN;
    float term = p * logf(p + EPS);

    #pragma unroll
    for (int off = 32; off > 0; off >>= 1) term += __shfl_down(term, off, 64);

    __shared__ float wsum[RED_THREADS / 64];
    int wave = t >> 6;
    int lane = t & 63;
    if (lane == 0) wsum[wave] = term;
    __syncthreads();

    if (t == 0) {
        float s = 0.0f;
        #pragma unroll
        for (int w = 0; w < RED_THREADS / 64; ++w) s += wsum[w];
        out[0] = expf(-s);
    }
}

extern "C" void kernel_launch(void* const* d_in, const int* in_sizes, int n_in,
                              void* d_out, int out_size, void* d_ws, size_t ws_size,
                              hipStream_t stream) {
    const int* indices = (const int*)d_in[0];
    int n = in_sizes[0];             // 16 * 1048576 = 16,777,216
    float* out = (float*)d_out;

    unsigned int* gpart = (unsigned int*)d_ws;                       // 1 MB
    unsigned int* cnt   = gpart + (size_t)HIST_BLOCKS * N_CODECS;    // 4 KB
    unsigned int* done  = cnt + N_CODECS;                            // 4 B

    int n4 = n >> 2;

    hist_partial_kernel<<<HIST_BLOCKS, HIST_THREADS, 0, stream>>>(
        indices, gpart, cnt, done, n4);
    reduce_finalize_kernel<<<RED_BLOCKS, RED_THREADS, 0, stream>>>(
        gpart, cnt, done, out, 1.0f / (float)n);
}

// Round 6
// 93.224 us; speedup vs baseline: 1.0306x; 1.0306x over previous
//
#include <hip/hip_runtime.h>
#include <hip/hip_bf16.h>

#define N_CODECS 1024
#define EPS 1e-8f
#define HIST_BLOCKS 1024
#define CHUNKS 16              // 1024 partials reduced in 16 chunks of 64

// ---------------------------------------------------------------------------
// Kernel 1: per-block LDS histogram -> private partial in d_ws (NO global
// atomics). Plain cached int4 loads (input is L3-resident after the harness's
// restore copy — do NOT use non-temporal loads, that bypasses L3: R5 showed
// +6us). Two independent loads per iteration for memory-level parallelism.
//
// Session elimination matrix (rounds 1-5): fusion/cooperative tails,
// 32-waves/CU occupancy, 8-deep load staging, and a provably conflict-free
// 32-way replicated LDS layout were ALL null or regressions. The hist floor
// is consistent with the per-CU DS-atomic retire rate (65536 lane-atomics/CU,
// invariant to banking/occupancy/ILP) + the input read — no source-level
// lever remains. This is the best measured configuration (93.5 us).
// ---------------------------------------------------------------------------
__global__ void __launch_bounds__(256) hist_partial_kernel(
        const int* __restrict__ idx,
        unsigned int* __restrict__ gpart,   // [HIST_BLOCKS][N_CODECS]
        int n4) {
    __shared__ unsigned int lcounts[N_CODECS];
    #pragma unroll
    for (int i = threadIdx.x; i < N_CODECS; i += 256) lcounts[i] = 0u;
    __syncthreads();

    const int4* __restrict__ idx4 = (const int4*)idx;
    const int stride = gridDim.x * 256;     // 262144
    for (int i = blockIdx.x * 256 + threadIdx.x; i < n4; i += 2 * stride) {
        int4 a = idx4[i];
        int j = i + stride;
        bool has_b = (j < n4);
        int4 b = has_b ? idx4[j] : make_int4(0, 0, 0, 0);

        atomicAdd(&lcounts[a.x], 1u);   // LDS atomics only
        atomicAdd(&lcounts[a.y], 1u);
        atomicAdd(&lcounts[a.z], 1u);
        atomicAdd(&lcounts[a.w], 1u);
        if (has_b) {
            atomicAdd(&lcounts[b.x], 1u);
            atomicAdd(&lcounts[b.y], 1u);
            atomicAdd(&lcounts[b.z], 1u);
            atomicAdd(&lcounts[b.w], 1u);
        }
    }
    __syncthreads();

    // contention-free merge: plain coalesced stores to this block's slice
    unsigned int* __restrict__ mypart = gpart + (size_t)blockIdx.x * N_CODECS;
    #pragma unroll
    for (int i = 0; i < N_CODECS / 256; ++i) {
        int b = i * 256 + threadIdx.x;
        mypart[b] = lcounts[b];
    }
}

// ---------------------------------------------------------------------------
// Kernel 2: reduce 1024 partials -> 16 chunk partials (column sums).
// Grid: 64 blocks x 256 threads. Block (c,q): chunk c=blk>>2, quarter q=blk&3.
// Thread handles bin = q*256 + tid, sums 64 partials. Fully coalesced.
// ---------------------------------------------------------------------------
__global__ void __launch_bounds__(256) reduce_kernel(
        const unsigned int* __restrict__ gpart,   // [HIST_BLOCKS][N_CODECS]
        unsigned int* __restrict__ p2) {          // [CHUNKS][N_CODECS]
    int c = blockIdx.x >> 2;
    int q = blockIdx.x & 3;
    int bin = q * 256 + threadIdx.x;

    const unsigned int* __restrict__ base = gpart + (size_t)(c * 64) * N_CODECS + bin;
    unsigned int s0 = 0, s1 = 0, s2 = 0, s3 = 0;
    #pragma unroll 4
    for (int k = 0; k < 64; k += 4) {
        s0 += base[(size_t)(k + 0) * N_CODECS];
        s1 += base[(size_t)(k + 1) * N_CODECS];
        s2 += base[(size_t)(k + 2) * N_CODECS];
        s3 += base[(size_t)(k + 3) * N_CODECS];
    }
    p2[c * N_CODECS + bin] = s0 + s1 + s2 + s3;
}

// ---------------------------------------------------------------------------
// Kernel 3: finalize. 1 block x 1024 threads: sum 16 chunk values per bin,
// p = count/N, term = p*log(p+eps), block reduce, out = exp(-sum).
// ---------------------------------------------------------------------------
__global__ void __launch_bounds__(1024) finalize_kernel(
        const unsigned int* __restrict__ p2,      // [CHUNKS][N_CODECS]
        float* __restrict__ out,
        float invN) {
    int t = threadIdx.x;
    unsigned int cnt = 0;
    #pragma unroll
    for (int c = 0; c < CHUNKS; ++c) cnt += p2[c * N_CODECS + t];

    float p = (float)cnt * invN;
    float term = p * logf(p + EPS);

    #pragma unroll
    for (int off = 32; off > 0; off >>= 1) term += __shfl_down(term, off, 64);

    __shared__ float wsum[16];
    int wave = t >> 6;
    int lane = t & 63;
    if (lane == 0) wsum[wave] = term;
    __syncthreads();

    if (wave == 0) {
        float s = (lane < 16) ? wsum[lane] : 0.0f;
        #pragma unroll
        for (int off = 8; off > 0; off >>= 1) s += __shfl_down(s, off, 64);
        if (lane == 0) out[0] = expf(-s);
    }
}

extern "C" void kernel_launch(void* const* d_in, const int* in_sizes, int n_in,
                              void* d_out, int out_size, void* d_ws, size_t ws_size,
                              hipStream_t stream) {
    const int* indices = (const int*)d_in[0];
    int n = in_sizes[0];             // 16 * 1048576 = 16,777,216
    float* out = (float*)d_out;

    unsigned int* gpart = (unsigned int*)d_ws;                       // 4 MB
    unsigned int* p2    = gpart + (size_t)HIST_BLOCKS * N_CODECS;    // 64 KB

    int n4 = n >> 2;

    hist_partial_kernel<<<HIST_BLOCKS, 256, 0, stream>>>(indices, gpart, n4);
    reduce_kernel<<<CHUNKS * 4, 256, 0, stream>>>(gpart, p2);
    finalize_kernel<<<1, 1024, 0, stream>>>(p2, out, 1.0f / (float)n);
}